// Round 3
// baseline (381.553 us; speedup 1.0000x reference)
//
#include <hip/hip_runtime.h>

// DecoderLSTM: B=4096, T=128 (127 steps), H=128, 4H=512, V=30, E=256.
// R3: wave-specialized. 256 blocks x 576 threads (9 waves).
//  - Waves 0-7: gates = Xproj[tok] (fp32, float4-gathered, prefetched) +
//    h @ W_hh^T via mfma_f32_16x16x32_bf16; W_hh frags live in registers all
//    127 steps; pointwise cell in C-layout regs; ONE barrier per step.
//  - Wave 8: logits (2 N-tiles in one wave) + in-register shuffle softmax +
//    CE, one step behind the core waves (reads the just-published h buffer).
// h double-buffered in LDS bf16 (row pad 136). Single setup kernel.

typedef __bf16 bf16x8 __attribute__((ext_vector_type(8)));
typedef float  f32x4  __attribute__((ext_vector_type(4)));

namespace {
constexpr int Bn = 4096, Tn = 128, Vn = 30, En = 256, Hn = 128, Gn = 512;
constexpr int WS_LOSS  = 0;
constexpr int WS_MASK  = 1;
constexpr int WS_XPROJ = 16;                  // 30*512 fp32, layout [v][k][g] (g=i,f,g,o)
constexpr int WS_WF_F  = WS_XPROJ + Vn * Gn;  // 65536 bf16 Whh-frags + 4096 bf16 Wlin-frags
}

__device__ __forceinline__ float fexp2(float x) { return __builtin_amdgcn_exp2f(x); }
__device__ __forceinline__ float frcp(float x)  { return __builtin_amdgcn_rcpf(x); }
__device__ __forceinline__ float sigf(float x)  { return frcp(1.f + fexp2(x * -1.44269504f)); }
__device__ __forceinline__ float tanh_(float x) { return 1.f - 2.f * frcp(fexp2(x * 2.88539008f) + 1.f); }

// ---- one setup kernel, 94 blocks x 256:
//  blocks 0-59:  Xproj[v][k][g] = dot(emb[v], W_ih[g*128+k]) + b_ih + b_hh
//  blocks 60-91: W_hh -> B-frag order (bf16): fid=((w*4+g)*4+kt)*64+l
//  blocks 92-93: W_lin -> B-frags (2 ntiles x 4 kt) + zero loss/mask accums
__global__ void k_setup(const float* __restrict__ emb, const float* __restrict__ W_ih,
                        const float* __restrict__ b_ih, const float* __restrict__ b_hh,
                        const float* __restrict__ W_hh, const float* __restrict__ W_lin,
                        float* __restrict__ ws) {
  const int bid = blockIdx.x, tid = threadIdx.x;
  if (bid < 60) {
    __shared__ __align__(16) float es[En];
    int v = bid >> 1;
    int j = ((bid & 1) << 8) + tid;   // j = g*128 + k
    es[tid] = emb[v * En + tid];
    __syncthreads();
    float a = b_ih[j] + b_hh[j];
    const float* wr = W_ih + j * En;
#pragma unroll 4
    for (int e = 0; e < En; e += 4) {
      float4 w = *(const float4*)(wr + e);
      float4 x = *(const float4*)(es + e);
      a += x.x * w.x + x.y * w.y + x.z * w.z + x.w * w.w;
    }
    ws[WS_XPROJ + v * Gn + (j & 127) * 4 + (j >> 7)] = a;
  } else if (bid < 92) {
    int fid = (bid - 60) * 256 + tid;  // 0..8191
    int l = fid & 63, kt = (fid >> 6) & 3, g = (fid >> 8) & 3, w = fid >> 10;
    int n  = (g * 8 + w) * 16 + (l & 15);
    int k0 = kt * 32 + (l >> 4) * 8;
    const float* src = W_hh + n * Hn + k0;
    union { __bf16 h[8]; uint4 u; } pk;
#pragma unroll
    for (int j = 0; j < 8; ++j) pk.h[j] = (__bf16)src[j];
    __bf16* wf = (__bf16*)(ws + WS_WF_F);
    *(uint4*)(wf + fid * 8) = pk.u;
  } else {
    int fid = (bid - 92) * 256 + tid;  // 0..511
    if (fid < 2) ws[fid] = 0.f;        // WS_LOSS, WS_MASK
    int l = fid & 63, kt = (fid >> 6) & 3, n = fid >> 8;
    int col = n * 16 + (l & 15);
    int k0  = kt * 32 + (l >> 4) * 8;
    union { __bf16 h[8]; uint4 u; } pk;
#pragma unroll
    for (int j = 0; j < 8; ++j)
      pk.h[j] = (col < Vn) ? (__bf16)W_lin[col * Hn + k0 + j] : (__bf16)0.f;
    __bf16* wf = (__bf16*)(ws + WS_WF_F);
    *(uint4*)(wf + 65536 + fid * 8) = pk.u;
  }
}

// ---- main: 256 blocks x 576 threads (9 waves), 16 batch rows/block
__global__ __launch_bounds__(576, 1) void k_main(
    const int* __restrict__ inpt, const float* __restrict__ h0,
    const float* __restrict__ c0, const float* __restrict__ maskY,
    const float* __restrict__ b_lin, float* __restrict__ ws) {
  __shared__ __align__(16) __bf16 hbuf[2][16][136];  // pad 136
  __shared__ int tok[16][Tn];

  const float*  Xp  = ws + WS_XPROJ;
  const float4* X4  = (const float4*)Xp;             // [v*128 + k] -> (i,f,g,o)
  const __bf16* wf  = (const __bf16*)(ws + WS_WF_F);
  const __bf16* wlf = wf + 65536;

  const int tid = threadIdx.x;
  const int w = tid >> 6, l = tid & 63, quad = l >> 4, lc = l & 15;
  const int row0 = blockIdx.x * 16;
  const int kh = w * 16 + lc;          // (core waves) owned h-column

  // staging (all 9 waves)
  for (int idx = tid; idx < 16 * Tn; idx += 576) {
    int r = idx >> 7, t = idx & 127;
    tok[r][t] = inpt[(row0 + r) * Tn + t];
  }
  for (int idx = tid; idx < 16 * Hn; idx += 576) {
    int r = idx >> 7, k = idx & 127;
    hbuf[0][r][k] = (__bf16)h0[(row0 + r) * Hn + k];
  }

  // role-specific register setup
  bf16x8 wfr[4][4];  // core: W_hh B-frags (held all 127 steps)
  float  creg[4];
  bf16x8 wlr[4][2];  // wave 8: W_lin B-frags [kt][ntile]
  float  bias0 = 0.f, bias1 = 0.f, mloc = 0.f;
  if (w < 8) {
#pragma unroll
    for (int g = 0; g < 4; ++g)
#pragma unroll
      for (int kt = 0; kt < 4; ++kt)
        wfr[g][kt] = __builtin_bit_cast(
            bf16x8, *(const uint4*)(wf + (((w * 4 + g) * 4 + kt) * 64 + l) * 8));
#pragma unroll
    for (int p = 0; p < 4; ++p)
      creg[p] = c0[(row0 + quad * 4 + p) * Hn + kh];
    if (w == 7) {  // block-local mask sum (full 16x128 chunk)
      float s = 0.f;
      const float4* m4 = (const float4*)(maskY + row0 * Tn);
#pragma unroll
      for (int i = 0; i < 8; ++i) s += m4[l + i * 64].x + m4[l + i * 64].y +
                                       m4[l + i * 64].z + m4[l + i * 64].w;
      mloc = s;
    }
  } else {
#pragma unroll
    for (int kt = 0; kt < 4; ++kt)
#pragma unroll
      for (int n = 0; n < 2; ++n)
        wlr[kt][n] = __builtin_bit_cast(
            bf16x8, *(const uint4*)(wlf + ((n * 4 + kt) * 64 + l) * 8));
    bias0 = b_lin[lc];
    bias1 = (lc + 16 < Vn) ? b_lin[lc + 16] : -1e30f;
  }
  float ce_acc = 0.f;
  __syncthreads();

  // initial Xproj prefetch (t=0)
  float4 xv[4];
  if (w < 8) {
#pragma unroll
    for (int p = 0; p < 4; ++p)
      xv[p] = X4[tok[quad * 4 + p][0] * 128 + kh];
  }

  for (int t = 0; t < Tn - 1; ++t) {
    const int par = t & 1;
    if (w < 8) {
      const __bf16* hc = &hbuf[par][0][0];
      __bf16*       hn = &hbuf[par ^ 1][0][0];

      bf16x8 af[4];
#pragma unroll
      for (int kt = 0; kt < 4; ++kt)
        af[kt] = __builtin_bit_cast(
            bf16x8, *(const uint4*)(hc + lc * 136 + kt * 32 + quad * 8));

      // prefetch Xproj for t+1 (t+1 <= 127 is a valid token column)
      float4 xn[4];
#pragma unroll
      for (int p = 0; p < 4; ++p)
        xn[p] = X4[tok[quad * 4 + p][t + 1] * 128 + kh];

      f32x4 acc[4] = {{0, 0, 0, 0}, {0, 0, 0, 0}, {0, 0, 0, 0}, {0, 0, 0, 0}};
#pragma unroll
      for (int g = 0; g < 4; ++g)
#pragma unroll
        for (int kt = 0; kt < 4; ++kt)
          acc[g] = __builtin_amdgcn_mfma_f32_16x16x32_bf16(af[kt], wfr[g][kt], acc[g], 0, 0, 0);

#pragma unroll
      for (int p = 0; p < 4; ++p) {
        float gi = acc[0][p] + xv[p].x;
        float gf = acc[1][p] + xv[p].y;
        float gg = acc[2][p] + xv[p].z;
        float go = acc[3][p] + xv[p].w;
        float c2 = sigf(gf) * creg[p] + sigf(gi) * tanh_(gg);
        float h2 = sigf(go) * tanh_(c2);
        creg[p] = c2;
        hn[(quad * 4 + p) * 136 + kh] = (__bf16)h2;
        xv[p] = xn[p];
      }
    }
    __syncthreads();  // the only barrier: h(t+1) published

    if (w == 8) {  // logits+softmax+CE for step t, from h(t+1), overlapped
      const __bf16* hn = &hbuf[par ^ 1][0][0];
      f32x4 lacc[2] = {{bias0, bias0, bias0, bias0}, {bias1, bias1, bias1, bias1}};
#pragma unroll
      for (int kt = 0; kt < 4; ++kt) {
        bf16x8 a2 = __builtin_bit_cast(
            bf16x8, *(const uint4*)(hn + lc * 136 + kt * 32 + quad * 8));
        lacc[0] = __builtin_amdgcn_mfma_f32_16x16x32_bf16(a2, wlr[kt][0], lacc[0], 0, 0, 0);
        lacc[1] = __builtin_amdgcn_mfma_f32_16x16x32_bf16(a2, wlr[kt][1], lacc[1], 0, 0, 0);
      }
#pragma unroll
      for (int p = 0; p < 4; ++p) {
        float a0 = lacc[0][p], a1 = lacc[1][p];
        float m = fmaxf(a0, a1);
        m = fmaxf(m, __shfl_xor(m, 1));
        m = fmaxf(m, __shfl_xor(m, 2));
        m = fmaxf(m, __shfl_xor(m, 4));
        m = fmaxf(m, __shfl_xor(m, 8));
        float e = fexp2((a0 - m) * 1.44269504f) + fexp2((a1 - m) * 1.44269504f);
        e += __shfl_xor(e, 1);
        e += __shfl_xor(e, 2);
        e += __shfl_xor(e, 4);
        e += __shfl_xor(e, 8);
        int r = quad * 4 + p;
        int y = tok[r][t + 1];
        float sel = (y < 16) ? a0 : a1;
        float ly = __shfl(sel, (l & 48) + (y & 15));
        float ce = (m + __logf(e)) - ly;
        if (lc == p) ce_acc += ce * maskY[(row0 + r) * Tn + t];
      }
    }
  }

  // reductions: wave 8 -> loss, wave 7 -> mask
  if (w == 8) {
#pragma unroll
    for (int off = 32; off > 0; off >>= 1) ce_acc += __shfl_down(ce_acc, off);
    if (l == 0) atomicAdd(ws + WS_LOSS, ce_acc);
  }
  if (w == 7) {
#pragma unroll
    for (int off = 32; off > 0; off >>= 1) mloc += __shfl_down(mloc, off);
    if (l == 0) atomicAdd(ws + WS_MASK, mloc);
  }
}

__global__ void k_final(const float* __restrict__ ws, float* __restrict__ out) {
  if (threadIdx.x == 0 && blockIdx.x == 0) out[0] = ws[WS_LOSS] / ws[WS_MASK];
}

extern "C" void kernel_launch(void* const* d_in, const int* in_sizes, int n_in,
                              void* d_out, int out_size, void* d_ws, size_t ws_size,
                              hipStream_t stream) {
  const int*   inpt  = (const int*)  d_in[0];
  const float* h0    = (const float*)d_in[1];
  const float* c0    = (const float*)d_in[2];
  const float* maskY = (const float*)d_in[3];
  // d_in[4] = beta (unused)
  const float* emb   = (const float*)d_in[5];
  const float* W_ih  = (const float*)d_in[6];
  const float* b_ih  = (const float*)d_in[7];
  const float* W_hh  = (const float*)d_in[8];
  const float* b_hh  = (const float*)d_in[9];
  const float* W_lin = (const float*)d_in[10];
  const float* b_lin = (const float*)d_in[11];
  float* ws  = (float*)d_ws;
  float* out = (float*)d_out;

  hipLaunchKernelGGL(k_setup, dim3(94),  dim3(256), 0, stream,
                     emb, W_ih, b_ih, b_hh, W_hh, W_lin, ws);
  hipLaunchKernelGGL(k_main,  dim3(256), dim3(576), 0, stream,
                     inpt, h0, c0, maskY, b_lin, ws);
  hipLaunchKernelGGL(k_final, dim3(1),   dim3(64),  0, stream, ws, out);
}

// Round 4
// 361.554 us; speedup vs baseline: 1.0553x; 1.0553x over previous
//
#include <hip/hip_runtime.h>

// DecoderLSTM: B=4096, T=128 (127 steps), H=128, 4H=512, V=30, E=256.
// R4: R3's wave-specialized pipeline (256 blocks x 576 thr, 9 waves,
// ONE barrier/step) with the register-spill fixed:
//  - Xproj folded into MFMA accumulator init (xv regs die before the chain)
//  - no t+1 prefetch registers
//  - wave 8's W_lin fragments live in LDS, not VGPRs
// Core waves 0-7: gates MFMA + pointwise cell (c in regs). Wave 8: logits
// MFMA + in-register shuffle softmax + CE, one step behind, overlapped.

typedef __bf16 bf16x8 __attribute__((ext_vector_type(8)));
typedef float  f32x4  __attribute__((ext_vector_type(4)));

namespace {
constexpr int Bn = 4096, Tn = 128, Vn = 30, En = 256, Hn = 128, Gn = 512;
constexpr int WS_LOSS  = 0;
constexpr int WS_MASK  = 1;
constexpr int WS_XPROJ = 16;                  // 30*512 fp32, layout [v][k][g]
constexpr int WS_WF_F  = WS_XPROJ + Vn * Gn;  // 65536 bf16 Whh-frags + 4096 bf16 Wlin-frags
}

__device__ __forceinline__ float fexp2(float x) { return __builtin_amdgcn_exp2f(x); }
__device__ __forceinline__ float frcp(float x)  { return __builtin_amdgcn_rcpf(x); }
__device__ __forceinline__ float sigf(float x)  { return frcp(1.f + fexp2(x * -1.44269504f)); }
__device__ __forceinline__ float tanh_(float x) { return 1.f - 2.f * frcp(fexp2(x * 2.88539008f) + 1.f); }

// ---- one setup kernel, 94 blocks x 256 (same as R3)
__global__ void k_setup(const float* __restrict__ emb, const float* __restrict__ W_ih,
                        const float* __restrict__ b_ih, const float* __restrict__ b_hh,
                        const float* __restrict__ W_hh, const float* __restrict__ W_lin,
                        float* __restrict__ ws) {
  const int bid = blockIdx.x, tid = threadIdx.x;
  if (bid < 60) {
    __shared__ __align__(16) float es[En];
    int v = bid >> 1;
    int j = ((bid & 1) << 8) + tid;   // j = g*128 + k
    es[tid] = emb[v * En + tid];
    __syncthreads();
    float a = b_ih[j] + b_hh[j];
    const float* wr = W_ih + j * En;
#pragma unroll 4
    for (int e = 0; e < En; e += 4) {
      float4 w = *(const float4*)(wr + e);
      float4 x = *(const float4*)(es + e);
      a += x.x * w.x + x.y * w.y + x.z * w.z + x.w * w.w;
    }
    ws[WS_XPROJ + v * Gn + (j & 127) * 4 + (j >> 7)] = a;
  } else if (bid < 92) {
    int fid = (bid - 60) * 256 + tid;  // 0..8191
    int l = fid & 63, kt = (fid >> 6) & 3, g = (fid >> 8) & 3, w = fid >> 10;
    int n  = (g * 8 + w) * 16 + (l & 15);
    int k0 = kt * 32 + (l >> 4) * 8;
    const float* src = W_hh + n * Hn + k0;
    union { __bf16 h[8]; uint4 u; } pk;
#pragma unroll
    for (int j = 0; j < 8; ++j) pk.h[j] = (__bf16)src[j];
    __bf16* wf = (__bf16*)(ws + WS_WF_F);
    *(uint4*)(wf + fid * 8) = pk.u;
  } else {
    int fid = (bid - 92) * 256 + tid;  // 0..511
    if (fid < 2) ws[fid] = 0.f;        // WS_LOSS, WS_MASK
    int l = fid & 63, kt = (fid >> 6) & 3, n = fid >> 8;
    int col = n * 16 + (l & 15);
    int k0  = kt * 32 + (l >> 4) * 8;
    union { __bf16 h[8]; uint4 u; } pk;
#pragma unroll
    for (int j = 0; j < 8; ++j)
      pk.h[j] = (col < Vn) ? (__bf16)W_lin[col * Hn + k0 + j] : (__bf16)0.f;
    __bf16* wf = (__bf16*)(ws + WS_WF_F);
    *(uint4*)(wf + 65536 + fid * 8) = pk.u;
  }
}

// ---- main: 256 blocks x 576 threads (9 waves), 16 batch rows/block
__global__ __launch_bounds__(576, 1) void k_main(
    const int* __restrict__ inpt, const float* __restrict__ h0,
    const float* __restrict__ c0, const float* __restrict__ maskY,
    const float* __restrict__ b_lin, float* __restrict__ ws) {
  __shared__ __align__(16) __bf16 hbuf[2][16][136];  // pad 136
  __shared__ __align__(16) __bf16 wls[4096];         // W_lin frags in LDS (8 KB)
  __shared__ int tok[16][Tn];

  const float4* X4 = (const float4*)(ws + WS_XPROJ); // [v*128 + k] -> (i,f,g,o)
  const __bf16* wf = (const __bf16*)(ws + WS_WF_F);

  const int tid = threadIdx.x;
  const int w = tid >> 6, l = tid & 63, quad = l >> 4, lc = l & 15;
  const int row0 = blockIdx.x * 16;
  const int kh = w * 16 + lc;

  // staging (all 9 waves): tok, h0, W_lin frags -> LDS
  for (int idx = tid; idx < 16 * Tn; idx += 576) {
    int r = idx >> 7, t = idx & 127;
    tok[r][t] = inpt[(row0 + r) * Tn + t];
  }
  for (int idx = tid; idx < 16 * Hn; idx += 576) {
    int r = idx >> 7, k = idx & 127;
    hbuf[0][r][k] = (__bf16)h0[(row0 + r) * Hn + k];
  }
  {
    const uint4* src = (const uint4*)(wf + 65536);
    uint4* dst = (uint4*)wls;
    for (int idx = tid; idx < 512; idx += 576) dst[idx] = src[idx];
  }

  // role-specific register setup
  bf16x8 wfr[4][4];  // core: W_hh B-frags, held all 127 steps (32 VGPRs)
  float  creg[4];
  float  bias0 = 0.f, bias1 = 0.f, mloc = 0.f;
  if (w < 8) {
#pragma unroll
    for (int g = 0; g < 4; ++g)
#pragma unroll
      for (int kt = 0; kt < 4; ++kt)
        wfr[g][kt] = __builtin_bit_cast(
            bf16x8, *(const uint4*)(wf + (((w * 4 + g) * 4 + kt) * 64 + l) * 8));
#pragma unroll
    for (int p = 0; p < 4; ++p)
      creg[p] = c0[(row0 + quad * 4 + p) * Hn + kh];
    if (w == 7) {  // block-local mask sum
      float s = 0.f;
      const float4* m4 = (const float4*)(maskY + row0 * Tn);
#pragma unroll
      for (int i = 0; i < 8; ++i) s += m4[l + i * 64].x + m4[l + i * 64].y +
                                       m4[l + i * 64].z + m4[l + i * 64].w;
      mloc = s;
    }
  } else {
    bias0 = b_lin[lc];
    bias1 = (lc + 16 < Vn) ? b_lin[lc + 16] : -1e30f;
  }
  float ce_acc = 0.f;
  __syncthreads();

  for (int t = 0; t < Tn - 1; ++t) {
    const int par = t & 1;
    if (w < 8) {
      const __bf16* hc = &hbuf[par][0][0];
      __bf16*       hn = &hbuf[par ^ 1][0][0];

      // Xproj gather first (longest latency), dies at accumulator init
      float4 xv[4];
#pragma unroll
      for (int p = 0; p < 4; ++p)
        xv[p] = X4[tok[quad * 4 + p][t] * 128 + kh];

      bf16x8 af[4];
#pragma unroll
      for (int kt = 0; kt < 4; ++kt)
        af[kt] = __builtin_bit_cast(
            bf16x8, *(const uint4*)(hc + lc * 136 + kt * 32 + quad * 8));

      // acc[g][p] lives at (row=quad*4+p, col=kh): init = Xproj addend
      f32x4 acc[4];
#pragma unroll
      for (int p = 0; p < 4; ++p) {
        acc[0][p] = xv[p].x; acc[1][p] = xv[p].y;
        acc[2][p] = xv[p].z; acc[3][p] = xv[p].w;
      }
#pragma unroll
      for (int g = 0; g < 4; ++g)
#pragma unroll
        for (int kt = 0; kt < 4; ++kt)
          acc[g] = __builtin_amdgcn_mfma_f32_16x16x32_bf16(af[kt], wfr[g][kt], acc[g], 0, 0, 0);

#pragma unroll
      for (int p = 0; p < 4; ++p) {
        float c2 = sigf(acc[1][p]) * creg[p] + sigf(acc[0][p]) * tanh_(acc[2][p]);
        float h2 = sigf(acc[3][p]) * tanh_(c2);
        creg[p] = c2;
        hn[(quad * 4 + p) * 136 + kh] = (__bf16)h2;
      }
    }
    __syncthreads();  // the only barrier: h(t+1) published

    if (w == 8) {  // logits+softmax+CE for step t from h(t+1), overlapped
      const __bf16* hn = &hbuf[par ^ 1][0][0];
      f32x4 lacc[2] = {{bias0, bias0, bias0, bias0}, {bias1, bias1, bias1, bias1}};
#pragma unroll
      for (int kt = 0; kt < 4; ++kt) {
        bf16x8 a2 = __builtin_bit_cast(
            bf16x8, *(const uint4*)(hn + lc * 136 + kt * 32 + quad * 8));
        bf16x8 w0 = __builtin_bit_cast(
            bf16x8, *(const uint4*)(wls + ((0 * 4 + kt) * 64 + l) * 8));
        bf16x8 w1 = __builtin_bit_cast(
            bf16x8, *(const uint4*)(wls + ((1 * 4 + kt) * 64 + l) * 8));
        lacc[0] = __builtin_amdgcn_mfma_f32_16x16x32_bf16(a2, w0, lacc[0], 0, 0, 0);
        lacc[1] = __builtin_amdgcn_mfma_f32_16x16x32_bf16(a2, w1, lacc[1], 0, 0, 0);
      }
#pragma unroll
      for (int p = 0; p < 4; ++p) {
        float a0 = lacc[0][p], a1 = lacc[1][p];
        float m = fmaxf(a0, a1);
        m = fmaxf(m, __shfl_xor(m, 1));
        m = fmaxf(m, __shfl_xor(m, 2));
        m = fmaxf(m, __shfl_xor(m, 4));
        m = fmaxf(m, __shfl_xor(m, 8));
        float e = fexp2((a0 - m) * 1.44269504f) + fexp2((a1 - m) * 1.44269504f);
        e += __shfl_xor(e, 1);
        e += __shfl_xor(e, 2);
        e += __shfl_xor(e, 4);
        e += __shfl_xor(e, 8);
        int r = quad * 4 + p;
        int y = tok[r][t + 1];
        float sel = (y < 16) ? a0 : a1;
        float ly = __shfl(sel, (l & 48) + (y & 15));
        float ce = (m + __logf(e)) - ly;
        if (lc == p) ce_acc += ce * maskY[(row0 + r) * Tn + t];
      }
    }
  }

  // reductions: wave 8 -> loss, wave 7 -> mask
  if (w == 8) {
#pragma unroll
    for (int off = 32; off > 0; off >>= 1) ce_acc += __shfl_down(ce_acc, off);
    if (l == 0) atomicAdd(ws + WS_LOSS, ce_acc);
  }
  if (w == 7) {
#pragma unroll
    for (int off = 32; off > 0; off >>= 1) mloc += __shfl_down(mloc, off);
    if (l == 0) atomicAdd(ws + WS_MASK, mloc);
  }
}

__global__ void k_final(const float* __restrict__ ws, float* __restrict__ out) {
  if (threadIdx.x == 0 && blockIdx.x == 0) out[0] = ws[WS_LOSS] / ws[WS_MASK];
}

extern "C" void kernel_launch(void* const* d_in, const int* in_sizes, int n_in,
                              void* d_out, int out_size, void* d_ws, size_t ws_size,
                              hipStream_t stream) {
  const int*   inpt  = (const int*)  d_in[0];
  const float* h0    = (const float*)d_in[1];
  const float* c0    = (const float*)d_in[2];
  const float* maskY = (const float*)d_in[3];
  // d_in[4] = beta (unused)
  const float* emb   = (const float*)d_in[5];
  const float* W_ih  = (const float*)d_in[6];
  const float* b_ih  = (const float*)d_in[7];
  const float* W_hh  = (const float*)d_in[8];
  const float* b_hh  = (const float*)d_in[9];
  const float* W_lin = (const float*)d_in[10];
  const float* b_lin = (const float*)d_in[11];
  float* ws  = (float*)d_ws;
  float* out = (float*)d_out;

  hipLaunchKernelGGL(k_setup, dim3(94),  dim3(256), 0, stream,
                     emb, W_ih, b_ih, b_hh, W_hh, W_lin, ws);
  hipLaunchKernelGGL(k_main,  dim3(256), dim3(576), 0, stream,
                     inpt, h0, c0, maskY, b_lin, ws);
  hipLaunchKernelGGL(k_final, dim3(1),   dim3(64),  0, stream, ws, out);
}

// Round 5
// 229.072 us; speedup vs baseline: 1.6656x; 1.5783x over previous
//
#include <hip/hip_runtime.h>

// DecoderLSTM: B=4096, T=128 (127 steps), H=128, 4H=512, V=30, E=256.
// R5: wave-specialized, balanced pipeline. 256 blocks x 576 thr (9 waves).
//  Waves 0-7 (step t): gates = Xproj[tok] (prefetched, acc-init) + h(t) @
//    W_hh^T (16 MFMA, W-frags in regs) -> pointwise cell -> h(t+1) to LDS.
//  Wave 8 (step t>=1): logits of h(t) (8 MFMA, W_lin frags in SAME reg array
//    as cores' W_hh - branch-exclusive union), softmax via LDS-transpose
//    (only 2 shfl rounds), CE from LDS-staged tok/mask. One barrier/step.
// Last block computes out = loss/mask via atomic completion counter.

typedef __bf16 bf16x8 __attribute__((ext_vector_type(8)));
typedef float  f32x4  __attribute__((ext_vector_type(4)));

namespace {
constexpr int Bn = 4096, Tn = 128, Vn = 30, En = 256, Hn = 128, Gn = 512;
constexpr int WS_LOSS  = 0;
constexpr int WS_MASK  = 1;
constexpr int WS_CNT   = 2;
constexpr int WS_XPROJ = 16;                  // 30*512 fp32, layout [v][k][g]
constexpr int WS_WF_F  = WS_XPROJ + Vn * Gn;  // 65536 bf16 Whh-frags + 4096 bf16 Wlin-frags
}

__device__ __forceinline__ float fexp2(float x) { return __builtin_amdgcn_exp2f(x); }
__device__ __forceinline__ float frcp(float x)  { return __builtin_amdgcn_rcpf(x); }
__device__ __forceinline__ float sigf(float x)  { return frcp(1.f + fexp2(x * -1.44269504f)); }
__device__ __forceinline__ float tanh_(float x) { return 1.f - 2.f * frcp(fexp2(x * 2.88539008f) + 1.f); }

// ---- setup, 94 blocks x 256 (R4 layout; zeroes loss/mask/cnt)
__global__ void k_setup(const float* __restrict__ emb, const float* __restrict__ W_ih,
                        const float* __restrict__ b_ih, const float* __restrict__ b_hh,
                        const float* __restrict__ W_hh, const float* __restrict__ W_lin,
                        float* __restrict__ ws) {
  const int bid = blockIdx.x, tid = threadIdx.x;
  if (bid < 60) {
    __shared__ __align__(16) float es[En];
    int v = bid >> 1;
    int j = ((bid & 1) << 8) + tid;   // j = g*128 + k
    es[tid] = emb[v * En + tid];
    __syncthreads();
    float a = b_ih[j] + b_hh[j];
    const float* wr = W_ih + j * En;
#pragma unroll 4
    for (int e = 0; e < En; e += 4) {
      float4 w = *(const float4*)(wr + e);
      float4 x = *(const float4*)(es + e);
      a += x.x * w.x + x.y * w.y + x.z * w.z + x.w * w.w;
    }
    ws[WS_XPROJ + v * Gn + (j & 127) * 4 + (j >> 7)] = a;
  } else if (bid < 92) {
    int fid = (bid - 60) * 256 + tid;  // 0..8191
    int l = fid & 63, kt = (fid >> 6) & 3, g = (fid >> 8) & 3, w = fid >> 10;
    int n  = (g * 8 + w) * 16 + (l & 15);
    int k0 = kt * 32 + (l >> 4) * 8;
    const float* src = W_hh + n * Hn + k0;
    union { __bf16 h[8]; uint4 u; } pk;
#pragma unroll
    for (int j = 0; j < 8; ++j) pk.h[j] = (__bf16)src[j];
    __bf16* wf = (__bf16*)(ws + WS_WF_F);
    *(uint4*)(wf + fid * 8) = pk.u;
  } else {
    int fid = (bid - 92) * 256 + tid;  // 0..511
    if (fid < 3) ws[fid] = 0.f;        // WS_LOSS, WS_MASK, WS_CNT
    int l = fid & 63, kt = (fid >> 6) & 3, n = fid >> 8;
    int col = n * 16 + (l & 15);
    int k0  = kt * 32 + (l >> 4) * 8;
    union { __bf16 h[8]; uint4 u; } pk;
#pragma unroll
    for (int j = 0; j < 8; ++j)
      pk.h[j] = (col < Vn) ? (__bf16)W_lin[col * Hn + k0 + j] : (__bf16)0.f;
    __bf16* wf = (__bf16*)(ws + WS_WF_F);
    *(uint4*)(wf + 65536 + fid * 8) = pk.u;
  }
}

// ---- main: 256 blocks x 576 threads (9 waves), 16 batch rows/block
__global__ __launch_bounds__(576, 1) void k_main(
    const int* __restrict__ inpt, const float* __restrict__ h0,
    const float* __restrict__ c0, const float* __restrict__ maskY,
    const float* __restrict__ b_lin, float* __restrict__ ws,
    float* __restrict__ out) {
  __shared__ __align__(16) __bf16 hbuf[2][16][136];  // 8.7 KB
  __shared__ int   tokL[16 * 129];                   // pad 129: conflict-free col reads
  __shared__ float maskL[16 * 132];                  // pad 132
  __shared__ __align__(16) float logits[16 * 36];    // pad 36: aligned b128 transpose reads
  __shared__ float red[2];

  const float4* X4 = (const float4*)(ws + WS_XPROJ); // [v*128 + k] -> (i,f,g,o)
  const __bf16* wf = (const __bf16*)(ws + WS_WF_F);
  const __bf16* wlf = wf + 65536;

  const int tid = threadIdx.x;
  const int w = tid >> 6, l = tid & 63, quad = l >> 4, lc = l & 15;
  const int row0 = blockIdx.x * 16;
  const int kh = w * 16 + lc;

  // staging (all 9 waves)
  for (int idx = tid; idx < 16 * Tn; idx += 576) {
    int r = idx >> 7, t = idx & 127;
    tokL[r * 129 + t]  = inpt[(row0 + r) * Tn + t];
    maskL[r * 132 + t] = maskY[(row0 + r) * Tn + t];
  }
  for (int idx = tid; idx < 16 * Hn; idx += 576) {
    int r = idx >> 7, k = idx & 127;
    hbuf[0][r][k] = (__bf16)h0[(row0 + r) * Hn + k];
  }

  // weight fragments: branch-exclusive union (cores: W_hh[4][4]; wave8: W_lin[2][4])
  bf16x8 wreg[4][4];
  float  creg[4];
  float  bias0 = 0.f, bias1 = 0.f, mloc = 0.f;
  if (w < 8) {
#pragma unroll
    for (int g = 0; g < 4; ++g)
#pragma unroll
      for (int kt = 0; kt < 4; ++kt)
        wreg[g][kt] = __builtin_bit_cast(
            bf16x8, *(const uint4*)(wf + (((w * 4 + g) * 4 + kt) * 64 + l) * 8));
#pragma unroll
    for (int p = 0; p < 4; ++p)
      creg[p] = c0[(row0 + quad * 4 + p) * Hn + kh];
    if (w == 7) {  // block-local mask sum (all 128 cols — reference divides by full sum)
      float s = 0.f;
      const float4* m4 = (const float4*)(maskY + row0 * Tn);
#pragma unroll
      for (int i = 0; i < 8; ++i) s += m4[l + i * 64].x + m4[l + i * 64].y +
                                       m4[l + i * 64].z + m4[l + i * 64].w;
      mloc = s;
    }
  } else {
#pragma unroll
    for (int n = 0; n < 2; ++n)
#pragma unroll
      for (int kt = 0; kt < 4; ++kt)
        wreg[n][kt] = __builtin_bit_cast(
            bf16x8, *(const uint4*)(wlf + ((n * 4 + kt) * 64 + l) * 8));
    bias0 = b_lin[lc];
    bias1 = (lc < Vn - 16) ? b_lin[lc + 16] : -1e30f;
  }
  float ce_acc = 0.f;
  __syncthreads();

  // Xproj preload for t=0 (cores)
  float4 xv[4];
  if (w < 8) {
#pragma unroll
    for (int p = 0; p < 4; ++p)
      xv[p] = X4[tokL[(quad * 4 + p) * 129] * 128 + kh];
  }

  for (int t = 0; t < Tn; ++t) {  // 128 iterations; cores act t<127, wave8 t>=1
    const int par = t & 1;
    const __bf16* hc = &hbuf[par][0][0];
    __bf16*       hn = &hbuf[par ^ 1][0][0];

    if (w < 8) {
      if (t < Tn - 1) {
        bf16x8 af[4];
#pragma unroll
        for (int kt = 0; kt < 4; ++kt)
          af[kt] = __builtin_bit_cast(
              bf16x8, *(const uint4*)(hc + lc * 136 + kt * 32 + quad * 8));

        // next-step token indices (LDS, issued early)
        int tk[4];
#pragma unroll
        for (int p = 0; p < 4; ++p) tk[p] = tokL[(quad * 4 + p) * 129 + t + 1];

        f32x4 acc[4];
#pragma unroll
        for (int p = 0; p < 4; ++p) {
          acc[0][p] = xv[p].x; acc[1][p] = xv[p].y;
          acc[2][p] = xv[p].z; acc[3][p] = xv[p].w;
        }
#pragma unroll
        for (int g = 0; g < 4; ++g)
#pragma unroll
          for (int kt = 0; kt < 4; ++kt)
            acc[g] = __builtin_amdgcn_mfma_f32_16x16x32_bf16(af[kt], wreg[g][kt], acc[g], 0, 0, 0);

        // prefetch Xproj for t+1 (drains at the barrier; zero exposure next step)
        float4 xn[4];
#pragma unroll
        for (int p = 0; p < 4; ++p) xn[p] = X4[tk[p] * 128 + kh];

#pragma unroll
        for (int p = 0; p < 4; ++p) {
          float c2 = sigf(acc[1][p]) * creg[p] + sigf(acc[0][p]) * tanh_(acc[2][p]);
          float h2 = sigf(acc[3][p]) * tanh_(c2);
          creg[p] = c2;
          hn[(quad * 4 + p) * 136 + kh] = (__bf16)h2;
          xv[p] = xn[p];
        }
      }
    } else if (t >= 1) {
      // logits of h(t) = CE for ref-step t-1; targets tok[:,t], mask[:,t-1]
      bf16x8 af[4];
#pragma unroll
      for (int kt = 0; kt < 4; ++kt)
        af[kt] = __builtin_bit_cast(
            bf16x8, *(const uint4*)(hc + lc * 136 + kt * 32 + quad * 8));
      f32x4 lacc[2] = {{bias0, bias0, bias0, bias0}, {bias1, bias1, bias1, bias1}};
#pragma unroll
      for (int kt = 0; kt < 4; ++kt) {
        lacc[0] = __builtin_amdgcn_mfma_f32_16x16x32_bf16(af[kt], wreg[0][kt], lacc[0], 0, 0, 0);
        lacc[1] = __builtin_amdgcn_mfma_f32_16x16x32_bf16(af[kt], wreg[1][kt], lacc[1], 0, 0, 0);
      }
      // C-layout -> LDS [row][v] (stride 36)
#pragma unroll
      for (int p = 0; p < 4; ++p) {
        logits[(quad * 4 + p) * 36 + lc]      = lacc[0][p];
        logits[(quad * 4 + p) * 36 + 16 + lc] = lacc[1][p];
      }
      // transpose-softmax: 4 lanes per row, 8 logits each, 2 shfl rounds
      int row = l >> 2, j = l & 3;
      float4 v0 = *(const float4*)(logits + row * 36 + j * 8);
      float4 v1 = *(const float4*)(logits + row * 36 + j * 8 + 4);
      float m = fmaxf(fmaxf(fmaxf(v0.x, v0.y), fmaxf(v0.z, v0.w)),
                      fmaxf(fmaxf(v1.x, v1.y), fmaxf(v1.z, v1.w)));
      m = fmaxf(m, __shfl_xor(m, 1));
      m = fmaxf(m, __shfl_xor(m, 2));
      float e = fexp2((v0.x - m) * 1.44269504f) + fexp2((v0.y - m) * 1.44269504f) +
                fexp2((v0.z - m) * 1.44269504f) + fexp2((v0.w - m) * 1.44269504f) +
                fexp2((v1.x - m) * 1.44269504f) + fexp2((v1.y - m) * 1.44269504f) +
                fexp2((v1.z - m) * 1.44269504f) + fexp2((v1.w - m) * 1.44269504f);
      e += __shfl_xor(e, 1);
      e += __shfl_xor(e, 2);
      if (j == 0) {
        int   y  = tokL[row * 129 + t];
        float ly = logits[row * 36 + y];
        float ce = (m + __logf(e)) - ly;
        ce_acc += ce * maskL[row * 132 + t - 1];
      }
    }
    __syncthreads();  // the only barrier: h(t+1) published / logits buffer reuse
  }

  // final reductions: wave 7 mask partial -> LDS; wave 8 reduces CE + finishes
  if (w == 7) {
#pragma unroll
    for (int off = 32; off > 0; off >>= 1) mloc += __shfl_down(mloc, off);
    if (l == 0) red[0] = mloc;
  }
  __syncthreads();
  if (w == 8) {
#pragma unroll
    for (int off = 32; off > 0; off >>= 1) ce_acc += __shfl_down(ce_acc, off);
    if (l == 0) {
      atomicAdd(ws + WS_LOSS, ce_acc);
      atomicAdd(ws + WS_MASK, red[0]);
      __threadfence();
      unsigned old = atomicAdd((unsigned*)(ws + WS_CNT), 1u);
      if (old == 255) {  // last block: publish result
        float lv = atomicAdd(ws + WS_LOSS, 0.f);
        float mv = atomicAdd(ws + WS_MASK, 0.f);
        out[0] = lv / mv;
      }
    }
  }
}

extern "C" void kernel_launch(void* const* d_in, const int* in_sizes, int n_in,
                              void* d_out, int out_size, void* d_ws, size_t ws_size,
                              hipStream_t stream) {
  const int*   inpt  = (const int*)  d_in[0];
  const float* h0    = (const float*)d_in[1];
  const float* c0    = (const float*)d_in[2];
  const float* maskY = (const float*)d_in[3];
  // d_in[4] = beta (unused)
  const float* emb   = (const float*)d_in[5];
  const float* W_ih  = (const float*)d_in[6];
  const float* b_ih  = (const float*)d_in[7];
  const float* W_hh  = (const float*)d_in[8];
  const float* b_hh  = (const float*)d_in[9];
  const float* W_lin = (const float*)d_in[10];
  const float* b_lin = (const float*)d_in[11];
  float* ws  = (float*)d_ws;
  float* out = (float*)d_out;

  hipLaunchKernelGGL(k_setup, dim3(94),  dim3(256), 0, stream,
                     emb, W_ih, b_ih, b_hh, W_hh, W_lin, ws);
  hipLaunchKernelGGL(k_main,  dim3(256), dim3(576), 0, stream,
                     inpt, h0, c0, maskY, b_lin, ws, out);
}